// Round 6
// baseline (187.035 us; speedup 1.0000x reference)
//
#include <hip/hip_runtime.h>
#include <math.h>

// NAMClassifier: B=16384 rows, F=256 independent 1->64->32->1 MLPs.
// R6: R5 structure (feature-per-wave, weights in regs, f16 packed layer-1,
// swapped-operand MFMA, b2 in C-operand) + occupancy fix (SPLITS 16->32,
// 8 blocks/CU), unroll-2 tile loop, and prep fused to one dispatch.

#define NAM_B   16384
#define NAM_F   256
#define SPLITS  32
#define RPS     (NAM_B / SPLITS)   // 512 rows per (feature, split) wave
#define TILES   (RPS / 16)         // 32
#define NGRP    8                  // partial accumulation groups

typedef __attribute__((ext_vector_type(8))) _Float16 f16x8;
typedef __attribute__((ext_vector_type(4))) _Float16 f16x4;
typedef __attribute__((ext_vector_type(2))) _Float16 f16x2;
typedef __attribute__((ext_vector_type(4))) float    f32x4;

// ---- fused prep: blocks [0,1024) x-transpose, [1024,1280) W2 pack,
//      [1280,1296) zero partial ----
__global__ __launch_bounds__(256) void nam_prep(
    const float* __restrict__ x, const float* __restrict__ W2,
    _Float16* __restrict__ xT, _Float16* __restrict__ w2p,
    float* __restrict__ partial) {
    __shared__ float xs[64][65];
    const int b = blockIdx.x;
    const int t = threadIdx.x;
    if (b < 1024) {
        // x[16384][256] f32 -> xT[256][16384] f16, 64x64 tiles via LDS
        const int r0 = (b & 255) * 64;
        const int c0 = (b >> 8) * 64;
        const int rr = t >> 4;
        const int cc = (t & 15) * 4;
        #pragma unroll
        for (int e = 0; e < 4; ++e) {
            const float4 v = *reinterpret_cast<const float4*>(
                x + (size_t)(r0 + rr + e*16) * NAM_F + c0 + cc);
            xs[rr + e*16][cc+0] = v.x; xs[rr + e*16][cc+1] = v.y;
            xs[rr + e*16][cc+2] = v.z; xs[rr + e*16][cc+3] = v.w;
        }
        __syncthreads();
        const int wc = t >> 4;
        const int j  = (t & 15) * 4;
        #pragma unroll
        for (int e = 0; e < 4; ++e) {
            const int c = wc + e*16;
            f16x4 o = {(_Float16)xs[j+0][c], (_Float16)xs[j+1][c],
                       (_Float16)xs[j+2][c], (_Float16)xs[j+3][c]};
            *reinterpret_cast<f16x4*>(xT + (size_t)(c0 + c) * NAM_B + r0 + j) = o;
        }
    } else if (b < 1280) {
        // W2[256][64][32] f32 -> f16 A-fragments [f][s][a][64 lanes][8]
        // elem j of lane L for (f,s,a): W2[f][s*32 + (L>>4)*8 + j][a*16 + (L&15)]
        const int f = b - 1024;
        const int s = t >> 7, a = (t >> 6) & 1, L = t & 63;
        const int hi = L >> 4, m = L & 15;
        const float* __restrict__ W2f = W2 + (size_t)f * (64*32);
        f16x8 o;
        #pragma unroll
        for (int j = 0; j < 8; ++j)
            o[j] = (_Float16)W2f[(s*32 + hi*8 + j)*32 + a*16 + m];
        *reinterpret_cast<f16x8*>(w2p + ((size_t)((f*2 + s)*2 + a)*64 + L) * 8) = o;
    } else {
        // zero partial: NGRP*B floats = 32768 float4 over 16 blocks x 256 thr
        const int i = (b - 1280) * 256 + t;
        float4* p4 = reinterpret_cast<float4*>(partial);
        #pragma unroll
        for (int e = 0; e < 8; ++e)
            p4[(size_t)i * 8 + e] = make_float4(0.f, 0.f, 0.f, 0.f);
    }
}

// ---- main: one feature per wave, 512 rows per wave ----
__global__ __launch_bounds__(256, 8) void nam_main(
    const float* __restrict__ W1, const float* __restrict__ b1,
    const float* __restrict__ b2, const float* __restrict__ W3,
    const _Float16* __restrict__ xT, const _Float16* __restrict__ w2p,
    float* __restrict__ partial) {
    const int t    = threadIdx.x;
    const int w    = t >> 6, lane = t & 63;
    const int f     = (blockIdx.x & 63) * 4 + w;   // feature owned by this wave
    const int split = blockIdx.x >> 6;             // 0..31 row split
    const int hi = lane >> 4, m = lane & 15;

    // ---- one-time weight loads into registers ----
    const f16x8* __restrict__ wp8 = reinterpret_cast<const f16x8*>(w2p);
    const size_t fb = (size_t)f * 4 * 64;
    const f16x8 a_s0a0 = wp8[fb + 0*64 + lane];
    const f16x8 a_s0a1 = wp8[fb + 1*64 + lane];
    const f16x8 a_s1a0 = wp8[fb + 2*64 + lane];
    const f16x8 a_s1a1 = wp8[fb + 3*64 + lane];

    const float* __restrict__ w1f = W1 + f * 64;
    const float* __restrict__ b1f = b1 + f * 64;
    f16x2 w1h[8], b1h[8];        // [s*4+u] = pair (s*32+hi*8+2u, +1)
    #pragma unroll
    for (int s = 0; s < 2; ++s)
        #pragma unroll
        for (int u = 0; u < 4; ++u) {
            const int h = s*32 + hi*8 + 2*u;
            w1h[s*4+u] = (f16x2){(_Float16)w1f[h], (_Float16)w1f[h+1]};
            b1h[s*4+u] = (f16x2){(_Float16)b1f[h], (_Float16)b1f[h+1]};
        }
    const f32x4 b2v0 = *reinterpret_cast<const f32x4*>(b2 + f*32 + hi*4);
    const f32x4 b2v1 = *reinterpret_cast<const f32x4*>(b2 + f*32 + 16 + hi*4);
    const f32x4 w3v0 = *reinterpret_cast<const f32x4*>(W3 + f*32 + hi*4);
    const f32x4 w3v1 = *reinterpret_cast<const f32x4*>(W3 + f*32 + 16 + hi*4);

    const _Float16* __restrict__ xcol = xT + (size_t)f * NAM_B + split * RPS + m;
    float* __restrict__ pout = partial + (size_t)(f & 7) * NAM_B + split * RPS;

    _Float16 xc = xcol[0];
    const f16x2 hzero = {(_Float16)0.f, (_Float16)0.f};
    #pragma unroll 2
    for (int tl = 0; tl < TILES; ++tl) {
        // prefetch next tile's x; final overread lands in w2p region (in ws)
        const _Float16 xn = xcol[(tl + 1) * 16];
        const f16x2 xb = {xc, xc};
        // B-frag = h1 (layer 1, packed f16): k = s*32+hi*8+j, col = row m
        union { f16x2 h[4]; f16x8 v; } bf0, bf1;
        #pragma unroll
        for (int u = 0; u < 4; ++u) {
            bf0.h[u] = __builtin_elementwise_max(xb * w1h[u]     + b1h[u],     hzero);
            bf1.h[u] = __builtin_elementwise_max(xb * w1h[4 + u] + b1h[4 + u], hzero);
        }
        // D[h2][row], b2 folded in via C-operand
        f32x4 acc0 = __builtin_amdgcn_mfma_f32_16x16x32_f16(a_s0a0, bf0.v, b2v0, 0,0,0);
        acc0       = __builtin_amdgcn_mfma_f32_16x16x32_f16(a_s1a0, bf1.v, acc0, 0,0,0);
        f32x4 acc1 = __builtin_amdgcn_mfma_f32_16x16x32_f16(a_s0a1, bf0.v, b2v1, 0,0,0);
        acc1       = __builtin_amdgcn_mfma_f32_16x16x32_f16(a_s1a1, bf1.v, acc1, 0,0,0);
        // layer 3: this lane's 8 h2 entries of row m
        float ts = 0.f;
        #pragma unroll
        for (int r = 0; r < 4; ++r) {
            ts = fmaf(fmaxf(acc0[r], 0.f), w3v0[r], ts);
            ts = fmaf(fmaxf(acc1[r], 0.f), w3v1[r], ts);
        }
        // reduce over h2 blocks (lanes differing in bits 4,5)
        ts += __shfl_xor(ts, 16);
        ts += __shfl_xor(ts, 32);
        if (hi == 0) atomicAdd(pout + tl*16 + m, ts);
        xc = xn;
    }
}

__global__ __launch_bounds__(256) void nam_phase2(
    const float* __restrict__ partial, const float* __restrict__ b3,
    const float* __restrict__ bias, float* __restrict__ out) {
    __shared__ float red[4];
    const int t = threadIdx.x;
    float v = b3[t];                       // F = 256 = blockDim
    #pragma unroll
    for (int off = 32; off; off >>= 1) v += __shfl_xor(v, off);
    if ((t & 63) == 0) red[t >> 6] = v;
    __syncthreads();
    const float sb3 = red[0] + red[1] + red[2] + red[3];
    const int b = blockIdx.x * 256 + t;
    float s = bias[0] + sb3;
    #pragma unroll
    for (int g = 0; g < NGRP; ++g) s += partial[(size_t)g * NAM_B + b];
    out[b] = s;
    out[NAM_B + b] = 1.0f / (1.0f + expf(-s));
}

extern "C" void kernel_launch(void* const* d_in, const int* in_sizes, int n_in,
                              void* d_out, int out_size, void* d_ws, size_t ws_size,
                              hipStream_t stream) {
    const float* x    = (const float*)d_in[0];
    const float* W1   = (const float*)d_in[1];
    const float* b1   = (const float*)d_in[2];
    const float* W2   = (const float*)d_in[3];
    const float* b2   = (const float*)d_in[4];
    const float* W3   = (const float*)d_in[5];
    const float* b3   = (const float*)d_in[6];
    const float* bias = (const float*)d_in[7];
    float* out = (float*)d_out;

    // ws layout: partial (512KB) | xT f16 (8MB) | w2p f16 (1MB)  = ~9.5MB
    float*    partial = (float*)d_ws;
    _Float16* xT  = (_Float16*)((char*)d_ws + (size_t)NGRP * NAM_B * 4);
    _Float16* w2p = (_Float16*)((char*)d_ws + (size_t)NGRP * NAM_B * 4
                                            + (size_t)NAM_F * NAM_B * 2);

    nam_prep<<<dim3(1296), 256, 0, stream>>>(x, W2, xT, w2p, partial);
    nam_main<<<dim3(SPLITS * 64), 256, 0, stream>>>(W1, b1, b2, W3, xT, w2p, partial);
    nam_phase2<<<dim3(NAM_B / 256), 256, 0, stream>>>(partial, b3, bias, out);
}

// Round 10
// 134.111 us; speedup vs baseline: 1.3946x; 1.3946x over previous
//
#include <hip/hip_runtime.h>
#include <math.h>

// NAMClassifier: B=16384 rows, F=256 independent 1->64->32->1 MLPs.
// R10 = R7 resubmit (4th infra timeout): atomic-free full fusion. Block = 64
// rows x 256 features; 8 waves, each wave = 32 features over the same 64 rows
// (4 MFMA sub-tiles of 16). Per-wave row sums stay in registers; one LDS
// reduce + sigmoid at the end writes d_out directly. 2 dispatches total.

#define NAM_B 16384
#define NAM_F 256
#define RPB   64               // rows per main block
#define NBLK  (NAM_B / RPB)    // 256
#define WAVES 8
#define FPW   (NAM_F / WAVES)  // 32 features per wave

typedef __attribute__((ext_vector_type(8))) _Float16 f16x8;
typedef __attribute__((ext_vector_type(4))) _Float16 f16x4;
typedef __attribute__((ext_vector_type(2))) _Float16 f16x2;
typedef __attribute__((ext_vector_type(4))) float    f32x4;

union pk8 { f16x8 v; f16x2 h[4]; };

// ---- prep: blocks [0,1024) x-transpose -> xT f16 [256][16384];
//      blocks [1024,1280): per-feature weight pack (w2p A-frags + w1p/b1p pairs)
__global__ __launch_bounds__(256) void nam_prep(
    const float* __restrict__ x,  const float* __restrict__ W2,
    const float* __restrict__ W1, const float* __restrict__ b1,
    _Float16* __restrict__ xT, _Float16* __restrict__ w2p,
    _Float16* __restrict__ w1p, _Float16* __restrict__ b1p) {
    __shared__ float xs[64][65];
    const int b = blockIdx.x;
    const int t = threadIdx.x;
    if (b < 1024) {
        // x[16384][256] f32 -> xT[256][16384] f16, 64x64 tiles via LDS
        const int r0 = (b & 255) * 64;
        const int c0 = (b >> 8) * 64;
        const int rr = t >> 4;
        const int cc = (t & 15) * 4;
        #pragma unroll
        for (int e = 0; e < 4; ++e) {
            const float4 v = *reinterpret_cast<const float4*>(
                x + (size_t)(r0 + rr + e*16) * NAM_F + c0 + cc);
            xs[rr + e*16][cc+0] = v.x; xs[rr + e*16][cc+1] = v.y;
            xs[rr + e*16][cc+2] = v.z; xs[rr + e*16][cc+3] = v.w;
        }
        __syncthreads();
        const int wc = t >> 4;
        const int j  = (t & 15) * 4;
        #pragma unroll
        for (int e = 0; e < 4; ++e) {
            const int c = wc + e*16;
            f16x4 o = {(_Float16)xs[j+0][c], (_Float16)xs[j+1][c],
                       (_Float16)xs[j+2][c], (_Float16)xs[j+3][c]};
            *reinterpret_cast<f16x4*>(xT + (size_t)(c0 + c) * NAM_B + r0 + j) = o;
        }
    } else {
        // W2[256][64][32] f32 -> f16 A-fragments [f*4 + s*2 + a][64 lanes][8]
        // elem j of lane L: W2[f][s*32 + (L>>4)*8 + j][a*16 + (L&15)]
        const int f = b - 1024;
        const int s = t >> 7, a = (t >> 6) & 1, L = t & 63;
        const int hi = L >> 4, m = L & 15;
        const float* __restrict__ W2f = W2 + (size_t)f * (64*32);
        f16x8 o;
        #pragma unroll
        for (int j = 0; j < 8; ++j)
            o[j] = (_Float16)W2f[(s*32 + hi*8 + j)*32 + a*16 + m];
        *reinterpret_cast<f16x8*>(w2p + ((size_t)(f*4 + s*2 + a)*64 + L) * 8) = o;
        // w1p/b1p: pre-paired f16, index [(f*2+s)*4+hi], elems j = src[f*64+s*32+hi*8+j]
        if (t < 16) {
            const int which = t >> 3;          // 0: W1, 1: b1
            const int s2 = (t >> 2) & 1, hi2 = t & 3;
            const float* __restrict__ src =
                (which ? b1 : W1) + f*64 + s2*32 + hi2*8;
            f16x8 o2;
            #pragma unroll
            for (int j = 0; j < 8; ++j) o2[j] = (_Float16)src[j];
            _Float16* dst = (which ? b1p : w1p) + ((size_t)(f*2 + s2)*4 + hi2)*8;
            *reinterpret_cast<f16x8*>(dst) = o2;
        }
    }
}

// ---- main: block = 64 rows x 256 features, writes final logits+probs ----
__global__ __launch_bounds__(512, 2) void nam_main(
    const float* __restrict__ b2, const float* __restrict__ W3,
    const float* __restrict__ b3, const float* __restrict__ bias,
    const _Float16* __restrict__ xT, const _Float16* __restrict__ w2p,
    const _Float16* __restrict__ w1p, const _Float16* __restrict__ b1p,
    float* __restrict__ out) {
    __shared__ float sred[WAVES][RPB];
    const int t = threadIdx.x;
    const int w = t >> 6, lane = t & 63;
    const int hi = lane >> 4, m = lane & 15;
    const int r0 = blockIdx.x * RPB;
    const int fbase = w * FPW;

    const f16x8* __restrict__ wp8 = reinterpret_cast<const f16x8*>(w2p);
    const f16x2 hzero = {(_Float16)0.f, (_Float16)0.f};

    float rs[4] = {0.f, 0.f, 0.f, 0.f};
    float b3sum = 0.f;

    #pragma unroll 2
    for (int i = 0; i < FPW; ++i) {
        const int f = fbase + i;
        // W2 A-fragments (16B vector loads, L2-resident after first touch)
        const f16x8 a00 = wp8[(size_t)(f*4 + 0)*64 + lane];
        const f16x8 a01 = wp8[(size_t)(f*4 + 1)*64 + lane];
        const f16x8 a10 = wp8[(size_t)(f*4 + 2)*64 + lane];
        const f16x8 a11 = wp8[(size_t)(f*4 + 3)*64 + lane];
        pk8 w10, w11, b10, b11;
        w10.v = *reinterpret_cast<const f16x8*>(w1p + ((size_t)(f*2+0)*4 + hi)*8);
        w11.v = *reinterpret_cast<const f16x8*>(w1p + ((size_t)(f*2+1)*4 + hi)*8);
        b10.v = *reinterpret_cast<const f16x8*>(b1p + ((size_t)(f*2+0)*4 + hi)*8);
        b11.v = *reinterpret_cast<const f16x8*>(b1p + ((size_t)(f*2+1)*4 + hi)*8);
        const f32x4 b2v0 = *reinterpret_cast<const f32x4*>(b2 + f*32 + hi*4);
        const f32x4 b2v1 = *reinterpret_cast<const f32x4*>(b2 + f*32 + 16 + hi*4);
        const f32x4 w3v0 = *reinterpret_cast<const f32x4*>(W3 + f*32 + hi*4);
        const f32x4 w3v1 = *reinterpret_cast<const f32x4*>(W3 + f*32 + 16 + hi*4);
        b3sum += b3[f];
        const _Float16* __restrict__ xcol = xT + (size_t)f * NAM_B + r0;

        #pragma unroll
        for (int sub = 0; sub < 4; ++sub) {
            const _Float16 xh = xcol[sub*16 + m];   // x[row r0+sub*16+m][f]
            const f16x2 xb = {xh, xh};
            // B-frag = h1 (layer 1, packed f16): col = m, k = s*32+hi*8+j
            pk8 bf0, bf1;
            #pragma unroll
            for (int u = 0; u < 4; ++u) {
                bf0.h[u] = __builtin_elementwise_max(xb * w10.h[u] + b10.h[u], hzero);
                bf1.h[u] = __builtin_elementwise_max(xb * w11.h[u] + b11.h[u], hzero);
            }
            // D[h2][row], b2 folded in via C-operand
            f32x4 acc0 = __builtin_amdgcn_mfma_f32_16x16x32_f16(a00, bf0.v, b2v0, 0,0,0);
            acc0       = __builtin_amdgcn_mfma_f32_16x16x32_f16(a10, bf1.v, acc0, 0,0,0);
            f32x4 acc1 = __builtin_amdgcn_mfma_f32_16x16x32_f16(a01, bf0.v, b2v1, 0,0,0);
            acc1       = __builtin_amdgcn_mfma_f32_16x16x32_f16(a11, bf1.v, acc1, 0,0,0);
            // layer 3 over this lane's 8 h2 entries of row m
            float ts = 0.f;
            #pragma unroll
            for (int r = 0; r < 4; ++r) {
                ts = fmaf(fmaxf(acc0[r], 0.f), w3v0[r], ts);
                ts = fmaf(fmaxf(acc1[r], 0.f), w3v1[r], ts);
            }
            ts += __shfl_xor(ts, 16);   // reduce over h2 blocks
            ts += __shfl_xor(ts, 32);
            rs[sub] += ts;
        }
    }

    if (hi == 0) {
        sred[w][ 0 + m] = rs[0] + b3sum;
        sred[w][16 + m] = rs[1] + b3sum;
        sred[w][32 + m] = rs[2] + b3sum;
        sred[w][48 + m] = rs[3] + b3sum;
    }
    __syncthreads();
    if (t < RPB) {
        float s = bias[0];
        #pragma unroll
        for (int ww = 0; ww < WAVES; ++ww) s += sred[ww][t];
        out[r0 + t] = s;
        out[NAM_B + r0 + t] = 1.0f / (1.0f + expf(-s));
    }
}

extern "C" void kernel_launch(void* const* d_in, const int* in_sizes, int n_in,
                              void* d_out, int out_size, void* d_ws, size_t ws_size,
                              hipStream_t stream) {
    const float* x    = (const float*)d_in[0];
    const float* W1   = (const float*)d_in[1];
    const float* b1   = (const float*)d_in[2];
    const float* W2   = (const float*)d_in[3];
    const float* b2   = (const float*)d_in[4];
    const float* W3   = (const float*)d_in[5];
    const float* b3   = (const float*)d_in[6];
    const float* bias = (const float*)d_in[7];
    float* out = (float*)d_out;

    // ws layout: xT f16 (8MB) | w2p f16 (1MB) | w1p (32KB) | b1p (32KB)
    _Float16* xT  = (_Float16*)d_ws;
    _Float16* w2p = xT  + (size_t)NAM_F * NAM_B;
    _Float16* w1p = w2p + (size_t)NAM_F * 64 * 32;
    _Float16* b1p = w1p + (size_t)NAM_F * 64;

    nam_prep<<<dim3(1280), 256, 0, stream>>>(x, W2, W1, b1, xT, w2p, w1p, b1p);
    nam_main<<<dim3(NBLK), 512, 0, stream>>>(b2, W3, b3, bias,
                                             xT, w2p, w1p, b1p, out);
}

// Round 11
// 114.054 us; speedup vs baseline: 1.6399x; 1.1759x over previous
//
#include <hip/hip_runtime.h>
#include <math.h>

// NAMClassifier: B=16384 rows, F=256 independent 1->64->32->1 MLPs.
// R11: occupancy fix via feature-split with PLAIN-STORE partials.
// Wave = 64 rows x 16 features; 4096 waves (512 blocks x 8 waves) = 4
// waves/SIMD (R7 had 2). Weight L2 traffic unchanged (depends on
// rows-per-wave only). One coalesced 128B x-load per feature + shfl
// broadcast replaces 4 narrow loads. Zero LDS / zero barriers in main.
// Tiny merge kernel (bias+sigmoid) — harness overhead is per-replay,
// not per-dispatch (R5/R6/R10 evidence), so 3 dispatches is fine.

#define NAM_B 16384
#define NAM_F 256
#define FPW   16               // features per wave
#define NFS   (NAM_F / FPW)    // 16 feature splits
#define RPW   64               // rows per wave
#define WPB   8                // waves per block
#define NBLK  ((NAM_B / RPW) * NFS / WPB)   // 512 blocks

typedef __attribute__((ext_vector_type(8))) _Float16 f16x8;
typedef __attribute__((ext_vector_type(4))) _Float16 f16x4;
typedef __attribute__((ext_vector_type(2))) _Float16 f16x2;
typedef __attribute__((ext_vector_type(4))) float    f32x4;

union pk8 { f16x8 v; f16x2 h[4]; };
union h2u { f16x2 h; unsigned u; };

// ---- prep: blocks [0,1024) x-transpose -> xT f16 [256][16384];
//      blocks [1024,1280): per-feature weight pack (w2p A-frags + w1p/b1p)
__global__ __launch_bounds__(256) void nam_prep(
    const float* __restrict__ x,  const float* __restrict__ W2,
    const float* __restrict__ W1, const float* __restrict__ b1,
    _Float16* __restrict__ xT, _Float16* __restrict__ w2p,
    _Float16* __restrict__ w1p, _Float16* __restrict__ b1p) {
    __shared__ float xs[64][65];
    const int b = blockIdx.x;
    const int t = threadIdx.x;
    if (b < 1024) {
        const int r0 = (b & 255) * 64;
        const int c0 = (b >> 8) * 64;
        const int rr = t >> 4;
        const int cc = (t & 15) * 4;
        #pragma unroll
        for (int e = 0; e < 4; ++e) {
            const float4 v = *reinterpret_cast<const float4*>(
                x + (size_t)(r0 + rr + e*16) * NAM_F + c0 + cc);
            xs[rr + e*16][cc+0] = v.x; xs[rr + e*16][cc+1] = v.y;
            xs[rr + e*16][cc+2] = v.z; xs[rr + e*16][cc+3] = v.w;
        }
        __syncthreads();
        const int wc = t >> 4;
        const int j  = (t & 15) * 4;
        #pragma unroll
        for (int e = 0; e < 4; ++e) {
            const int c = wc + e*16;
            f16x4 o = {(_Float16)xs[j+0][c], (_Float16)xs[j+1][c],
                       (_Float16)xs[j+2][c], (_Float16)xs[j+3][c]};
            *reinterpret_cast<f16x4*>(xT + (size_t)(c0 + c) * NAM_B + r0 + j) = o;
        }
    } else {
        // W2 -> f16 A-fragments [f*4 + s*2 + a][64 lanes][8]
        const int f = b - 1024;
        const int s = t >> 7, a = (t >> 6) & 1, L = t & 63;
        const int hi = L >> 4, m = L & 15;
        const float* __restrict__ W2f = W2 + (size_t)f * (64*32);
        f16x8 o;
        #pragma unroll
        for (int j = 0; j < 8; ++j)
            o[j] = (_Float16)W2f[(s*32 + hi*8 + j)*32 + a*16 + m];
        *reinterpret_cast<f16x8*>(w2p + ((size_t)(f*4 + s*2 + a)*64 + L) * 8) = o;
        if (t < 16) {
            const int which = t >> 3;          // 0: W1, 1: b1
            const int s2 = (t >> 2) & 1, hi2 = t & 3;
            const float* __restrict__ src =
                (which ? b1 : W1) + f*64 + s2*32 + hi2*8;
            f16x8 o2;
            #pragma unroll
            for (int j = 0; j < 8; ++j) o2[j] = (_Float16)src[j];
            _Float16* dst = (which ? b1p : w1p) + ((size_t)(f*2 + s2)*4 + hi2)*8;
            *reinterpret_cast<f16x8*>(dst) = o2;
        }
    }
}

// ---- main: wave = 64 rows x 16 features; plain-store partials ----
__global__ __launch_bounds__(512, 4) void nam_main(
    const float* __restrict__ b2, const float* __restrict__ W3,
    const float* __restrict__ b3,
    const _Float16* __restrict__ xT, const _Float16* __restrict__ w2p,
    const _Float16* __restrict__ w1p, const _Float16* __restrict__ b1p,
    float* __restrict__ partial) {   // [NFS][NAM_B]
    const int t = threadIdx.x;
    const int w = t >> 6, lane = t & 63;
    const int hi = lane >> 4, m = lane & 15;
    const int fs  = blockIdx.x >> 5;                 // 0..15 feature split
    const int r0  = ((blockIdx.x & 31) * WPB + w) * RPW;
    const int fbase = fs * FPW;

    const f16x8* __restrict__ wp8 = reinterpret_cast<const f16x8*>(w2p);
    const f16x2 hzero = {(_Float16)0.f, (_Float16)0.f};
    const unsigned short* __restrict__ xu =
        reinterpret_cast<const unsigned short*>(xT);

    float rs[4] = {0.f, 0.f, 0.f, 0.f};
    float b3sum = 0.f;

    // prefetch feature 0's x column (64 rows, one coalesced 128B load)
    unsigned xv = xu[(size_t)fbase * NAM_B + r0 + lane];

    #pragma unroll 2
    for (int i = 0; i < FPW; ++i) {
        const int f = fbase + i;
        const int inext = (i + 1 < FPW) ? (i + 1) : (FPW - 1);
        const unsigned xv_n = xu[(size_t)(fbase + inext) * NAM_B + r0 + lane];

        const f16x8 a00 = wp8[(size_t)(f*4 + 0)*64 + lane];
        const f16x8 a01 = wp8[(size_t)(f*4 + 1)*64 + lane];
        const f16x8 a10 = wp8[(size_t)(f*4 + 2)*64 + lane];
        const f16x8 a11 = wp8[(size_t)(f*4 + 3)*64 + lane];
        pk8 w10, w11, b10, b11;
        w10.v = *reinterpret_cast<const f16x8*>(w1p + ((size_t)(f*2+0)*4 + hi)*8);
        w11.v = *reinterpret_cast<const f16x8*>(w1p + ((size_t)(f*2+1)*4 + hi)*8);
        b10.v = *reinterpret_cast<const f16x8*>(b1p + ((size_t)(f*2+0)*4 + hi)*8);
        b11.v = *reinterpret_cast<const f16x8*>(b1p + ((size_t)(f*2+1)*4 + hi)*8);
        const f32x4 b2v0 = *reinterpret_cast<const f32x4*>(b2 + f*32 + hi*4);
        const f32x4 b2v1 = *reinterpret_cast<const f32x4*>(b2 + f*32 + 16 + hi*4);
        const f32x4 w3v0 = *reinterpret_cast<const f32x4*>(W3 + f*32 + hi*4);
        const f32x4 w3v1 = *reinterpret_cast<const f32x4*>(W3 + f*32 + 16 + hi*4);
        b3sum += b3[f];

        #pragma unroll
        for (int sub = 0; sub < 4; ++sub) {
            // broadcast x[row r0+sub*16+m][f] from lane sub*16+m
            h2u xb;
            const unsigned bits = (unsigned)__shfl((int)xv, sub*16 + m);
            xb.u = bits * 0x10001u;          // pack {h,h}
            pk8 bf0, bf1;
            #pragma unroll
            for (int u = 0; u < 4; ++u) {
                bf0.h[u] = __builtin_elementwise_max(xb.h * w10.h[u] + b10.h[u], hzero);
                bf1.h[u] = __builtin_elementwise_max(xb.h * w11.h[u] + b11.h[u], hzero);
            }
            f32x4 acc0 = __builtin_amdgcn_mfma_f32_16x16x32_f16(a00, bf0.v, b2v0, 0,0,0);
            acc0       = __builtin_amdgcn_mfma_f32_16x16x32_f16(a10, bf1.v, acc0, 0,0,0);
            f32x4 acc1 = __builtin_amdgcn_mfma_f32_16x16x32_f16(a01, bf0.v, b2v1, 0,0,0);
            acc1       = __builtin_amdgcn_mfma_f32_16x16x32_f16(a11, bf1.v, acc1, 0,0,0);
            float ts = 0.f;
            #pragma unroll
            for (int r = 0; r < 4; ++r) {
                ts = fmaf(fmaxf(acc0[r], 0.f), w3v0[r], ts);
                ts = fmaf(fmaxf(acc1[r], 0.f), w3v1[r], ts);
            }
            ts += __shfl_xor(ts, 16);   // reduce over h2 blocks
            ts += __shfl_xor(ts, 32);
            rs[sub] += ts;
        }
        xv = xv_n;
    }

    // after the xor-reduce all lanes of a 16-group hold the same sub value:
    // lane L stores row r0+L -> one coalesced 256B store per wave
    float vsel = (lane < 16) ? rs[0] : (lane < 32) ? rs[1]
               : (lane < 48) ? rs[2] : rs[3];
    partial[(size_t)fs * NAM_B + r0 + lane] = vsel + b3sum;
}

// ---- merge: bias + sum 16 splits + sigmoid ----
__global__ __launch_bounds__(256) void nam_merge(
    const float* __restrict__ partial, const float* __restrict__ bias,
    float* __restrict__ out) {
    const int r = blockIdx.x * 256 + threadIdx.x;
    float s = bias[0];
    #pragma unroll
    for (int g = 0; g < NFS; ++g) s += partial[(size_t)g * NAM_B + r];
    out[r] = s;
    out[NAM_B + r] = 1.0f / (1.0f + expf(-s));
}

extern "C" void kernel_launch(void* const* d_in, const int* in_sizes, int n_in,
                              void* d_out, int out_size, void* d_ws, size_t ws_size,
                              hipStream_t stream) {
    const float* x    = (const float*)d_in[0];
    const float* W1   = (const float*)d_in[1];
    const float* b1   = (const float*)d_in[2];
    const float* W2   = (const float*)d_in[3];
    const float* b2   = (const float*)d_in[4];
    const float* W3   = (const float*)d_in[5];
    const float* b3   = (const float*)d_in[6];
    const float* bias = (const float*)d_in[7];
    float* out = (float*)d_out;

    // ws: xT 8MB | w2p 1MB | w1p 32KB | b1p 32KB | partial 1MB  = ~10.1MB
    _Float16* xT  = (_Float16*)d_ws;
    _Float16* w2p = xT  + (size_t)NAM_F * NAM_B;
    _Float16* w1p = w2p + (size_t)NAM_F * 64 * 32;
    _Float16* b1p = w1p + (size_t)NAM_F * 64;
    float* partial = (float*)(b1p + (size_t)NAM_F * 64);

    nam_prep<<<dim3(1280), 256, 0, stream>>>(x, W2, W1, b1, xT, w2p, w1p, b1p);
    nam_main<<<dim3(NBLK), 512, 0, stream>>>(b2, W3, b3, xT, w2p, w1p, b1p, partial);
    nam_merge<<<dim3(NAM_B / 256), 256, 0, stream>>>(partial, bias, out);
}